// Round 3
// baseline (369.883 us; speedup 1.0000x reference)
//
#include <hip/hip_runtime.h>

// EdgeConv with KNN graph: B=8, N=4096, D=3, E=64, K=32.
// One wave per point. Batch staged in LDS as float4 (x,y,z,sq) — sq
// precomputed with the same fmaf chain used for the query, so self-dist is
// exactly 0. Per lane: 64 candidate distance keys in REGISTERS (launch_bounds
// 512,4 -> 128-VGPR budget, no spill). Exact top-32 via:
//   1) wave-uniform threshold search (count-below + octave gallop + binary
//      refine) until candidate pool <= 64,
//   2) pool compaction (per-wave LDS, atomic append),
//   3) 64-lane bitonic sort by (key, idx) -> lanes 0..31 = K nearest with
//      jax.lax.top_k's lower-index tie-break.

#define NPTS 4096
#define KNN  32

#define WFENCE() __asm__ volatile("s_waitcnt lgkmcnt(0)" ::: "memory")

__global__ __launch_bounds__(512, 4)
void edgeconv_knn_kernel(const float* __restrict__ x,
                         const float* __restrict__ theta_w,
                         const float* __restrict__ theta_b,
                         const float* __restrict__ phi_w,
                         const float* __restrict__ phi_b,
                         float* __restrict__ out)
{
    __shared__ float4 s_p[NPTS];               // 64 KB: x,y,z,sq
    __shared__ unsigned int s_poolk[8][64];    // 2 KB  per-wave pool keys
    __shared__ unsigned int s_pooli[8][64];    // 2 KB  per-wave pool indices
    __shared__ unsigned int s_cnt[8];          // 32 B

    const int tid  = threadIdx.x;
    const int wv   = tid >> 6;
    const int lane = tid & 63;

    const int b  = blockIdx.x >> 7;            // 128 WGs per batch
    const int i0 = (blockIdx.x & 127) << 5;    // 32 points per WG

    // lane == output channel e
    const float tw0 = theta_w[lane];
    const float tw1 = theta_w[64 + lane];
    const float tw2 = theta_w[128 + lane];
    const float tbv = theta_b[lane];
    const float pw0 = phi_w[lane];
    const float pw1 = phi_w[64 + lane];
    const float pw2 = phi_w[128 + lane];
    const float pbv = phi_b[lane];

    const float* xb = x + (size_t)b * NPTS * 3;
    for (int p = tid; p < NPTS; p += 512) {
        const float px = xb[p * 3 + 0];
        const float py = xb[p * 3 + 1];
        const float pz = xb[p * 3 + 2];
        const float sq = fmaf(pz, pz, fmaf(py, py, px * px));
        s_p[p] = make_float4(px, py, pz, sq);
    }
    __syncthreads();

    for (int r = 0; r < 4; ++r) {
        const int i = i0 + wv * 4 + r;
        const float4 P = s_p[i];               // x,y,z,sq of query point

        // ---- phase A: 64 distance keys per lane, j = s*64+lane ----
        unsigned int key[64];
        #pragma unroll 8
        for (int s = 0; s < 64; ++s) {
            const float4 Q = s_p[(s << 6) + lane];
            const float dt = fmaf(P.z, Q.z, fmaf(P.y, Q.y, P.x * Q.x));
            float dist = (P.w + Q.w) - 2.0f * dt;
            dist = fmaxf(dist, 0.0f);          // nonneg -> uint order == float order
            key[s] = __float_as_uint(dist);
        }

        // ---- min nonzero key -> starting octave ----
        unsigned int mn = 0xFFFFFFFFu;
        #pragma unroll
        for (int s = 0; s < 64; ++s) {
            const unsigned int k2 = key[s];
            if (k2 != 0u) mn = min(mn, k2);
        }
        #pragma unroll
        for (int off = 1; off < 64; off <<= 1)
            mn = min(mn, (unsigned int)__shfl_xor((int)mn, off, 64));

        auto cnt_lt = [&](unsigned int T) -> unsigned int {
            unsigned int c = 0;
            #pragma unroll
            for (int s = 0; s < 64; ++s) c += (key[s] < T) ? 1u : 0u;
            #pragma unroll
            for (int off = 1; off < 64; off <<= 1)
                c += (unsigned int)__shfl_xor((int)c, off, 64);
            return c;
        };

        // ---- gallop up by accelerating octaves until count >= K ----
        unsigned int L = mn & 0xFF800000u;
        unsigned int H = L;
        unsigned int stepOct = 1u << 23;
        unsigned int c;
        do {
            unsigned int Hn = H + stepOct;
            if (Hn > 0x7F800000u || Hn < H) Hn = 0x7F800000u;
            L = H; H = Hn;
            stepOct <<= 1;
            c = cnt_lt(H);
        } while (c < KNN);

        // ---- binary refine until pool fits in 64 lanes ----
        while (c > 64u && (H - L) > 1u) {
            const unsigned int M = L + ((H - L) >> 1);
            const unsigned int cm = cnt_lt(M);
            if (cm >= KNN) { H = M; c = cm; } else { L = M; }
        }

        // ---- pool build: all keys < H appended to per-wave LDS pool ----
        if (lane == 0) s_cnt[wv] = 0u;
        WFENCE();
        #pragma unroll
        for (int s = 0; s < 64; ++s) {
            if (key[s] < H) {
                const unsigned int p = atomicAdd(&s_cnt[wv], 1u);
                if (p < 64u) {
                    s_poolk[wv][p] = key[s];
                    s_pooli[wv][p] = (unsigned int)((s << 6) + lane);
                }
            }
        }
        WFENCE();
        unsigned int m = s_cnt[wv];
        if (m > 64u) m = 64u;

        unsigned int myk, myj;
        if ((unsigned int)lane < m) {
            myk = s_poolk[wv][lane];
            myj = s_pooli[wv][lane];
        } else {
            myk = 0xFFFFFFFFu;
            myj = (unsigned int)(NPTS + lane);   // unique, sorts last
        }

        // ---- 64-lane bitonic sort ascending by (key, idx) ----
        #pragma unroll
        for (int k = 2; k <= 64; k <<= 1) {
            #pragma unroll
            for (int jj = k >> 1; jj >= 1; jj >>= 1) {
                const unsigned int ok = (unsigned int)__shfl_xor((int)myk, jj, 64);
                const unsigned int oj = (unsigned int)__shfl_xor((int)myj, jj, 64);
                const bool up      = ((lane & k) == 0);
                const bool first   = ((lane & jj) == 0);
                const bool wantmin = (first == up);
                const bool less    = (myk < ok) || (myk == ok && myj < oj);
                if (less != wantmin) { myk = ok; myj = oj; }
            }
        }
        // lanes 0..31 hold the 32 nearest neighbors' indices in myj

        // ---- neighbor deltas (lanes 0..31) -> readlane broadcast ----
        float dx = 0.f, dy = 0.f, dz = 0.f;
        if (lane < KNN) {
            const float4 Q = s_p[myj];
            dx = Q.x - P.x;
            dy = Q.y - P.y;
            dz = Q.z - P.z;
        }

        const float basev = tbv + pbv + fmaf(pw2, P.z, fmaf(pw1, P.y, pw0 * P.x));
        float mx = -3.0e38f;
        #pragma unroll
        for (int t = 0; t < KNN; ++t) {
            const float ndx = __builtin_bit_cast(float, __builtin_amdgcn_readlane(__builtin_bit_cast(int, dx), t));
            const float ndy = __builtin_bit_cast(float, __builtin_amdgcn_readlane(__builtin_bit_cast(int, dy), t));
            const float ndz = __builtin_bit_cast(float, __builtin_amdgcn_readlane(__builtin_bit_cast(int, dz), t));
            const float proj = fmaf(tw2, ndz, fmaf(tw1, ndy, tw0 * ndx));
            mx = fmaxf(mx, proj);
        }
        out[(((size_t)b * NPTS + (size_t)i) << 6) + lane] = mx + basev;
        WFENCE();   // pool LDS reused next r-iteration (wave-local ordering)
    }
}

extern "C" void kernel_launch(void* const* d_in, const int* in_sizes, int n_in,
                              void* d_out, int out_size, void* d_ws, size_t ws_size,
                              hipStream_t stream) {
    const float* x  = (const float*)d_in[0];
    const float* tw = (const float*)d_in[1];
    const float* tb = (const float*)d_in[2];
    const float* pw = (const float*)d_in[3];
    const float* pb = (const float*)d_in[4];
    float* out = (float*)d_out;

    dim3 grid(8 * (NPTS / 32));   // 1024 WGs: 128 per batch, 32 points each
    dim3 block(512);
    hipLaunchKernelGGL(edgeconv_knn_kernel, grid, block, 0, stream,
                       x, tw, tb, pw, pb, out);
}

// Round 4
// 186.619 us; speedup vs baseline: 1.9820x; 1.9820x over previous
//
#include <hip/hip_runtime.h>

// EdgeConv with KNN graph: B=8, N=4096, D=3, E=64, K=32.
// One wave per point. Batch staged in LDS as float4 (x,y,z,sq); sq uses the
// same fmaf chain as the query so self-dist is exactly 0. Per lane: 64
// candidate distance keys in REGISTERS.
//   SPILL DISCIPLINE (R1/R2/R3 evidence): key[] stays in VGPRs ONLY if
//   (a) every loop touching key[] is FULLY unrolled (partial unroll ->
//       dynamic index -> scratch, 955 MB HBM traffic in R3), and
//   (b) the launch_bounds VGPR budget is >= ~110 (85 in R2 -> allocator
//       spilled ~40 regs, 330 MB traffic). (512,4) -> 128-VGPR budget.
// Exact top-32: wave-uniform threshold search (count-below + octave gallop +
// binary refine) -> pool <= 64 -> 64-lane bitonic by (key, idx) -> lanes
// 0..31 hold the K nearest with jax.lax.top_k's lower-index tie-break.

#define NPTS 4096
#define KNN  32

#define WFENCE() __asm__ volatile("s_waitcnt lgkmcnt(0)" ::: "memory")

__global__ __launch_bounds__(512, 4)
void edgeconv_knn_kernel(const float* __restrict__ x,
                         const float* __restrict__ theta_w,
                         const float* __restrict__ theta_b,
                         const float* __restrict__ phi_w,
                         const float* __restrict__ phi_b,
                         float* __restrict__ out)
{
    __shared__ float4 s_p[NPTS];               // 64 KB: x,y,z,sq
    __shared__ unsigned int s_poolk[8][64];    // 2 KB  per-wave pool keys
    __shared__ unsigned int s_pooli[8][64];    // 2 KB  per-wave pool indices
    __shared__ unsigned int s_cnt[8];          // 32 B

    const int tid  = threadIdx.x;
    const int wv   = tid >> 6;
    const int lane = tid & 63;

    const int b  = blockIdx.x >> 7;            // 128 WGs per batch
    const int i0 = (blockIdx.x & 127) << 5;    // 32 points per WG

    // lane == output channel e
    const float tw0 = theta_w[lane];
    const float tw1 = theta_w[64 + lane];
    const float tw2 = theta_w[128 + lane];
    const float tbv = theta_b[lane];
    const float pw0 = phi_w[lane];
    const float pw1 = phi_w[64 + lane];
    const float pw2 = phi_w[128 + lane];
    const float pbv = phi_b[lane];

    const float* xb = x + (size_t)b * NPTS * 3;
    for (int p = tid; p < NPTS; p += 512) {
        const float px = xb[p * 3 + 0];
        const float py = xb[p * 3 + 1];
        const float pz = xb[p * 3 + 2];
        const float sq = fmaf(pz, pz, fmaf(py, py, px * px));
        s_p[p] = make_float4(px, py, pz, sq);
    }
    __syncthreads();

    for (int r = 0; r < 4; ++r) {
        const int i = i0 + wv * 4 + r;
        const float4 P = s_p[i];               // x,y,z,sq of query point

        // ---- phase A: 64 distance keys per lane, j = s*64+lane ----
        // FULL unroll: key[s] must be a constant index everywhere.
        unsigned int key[64];
        #pragma unroll
        for (int s = 0; s < 64; ++s) {
            const float4 Q = s_p[(s << 6) + lane];
            const float dt = fmaf(P.z, Q.z, fmaf(P.y, Q.y, P.x * Q.x));
            float dist = (P.w + Q.w) - 2.0f * dt;
            dist = fmaxf(dist, 0.0f);          // nonneg -> uint order == float order
            key[s] = __float_as_uint(dist);
        }

        // ---- min nonzero key -> starting octave ----
        unsigned int mn = 0xFFFFFFFFu;
        #pragma unroll
        for (int s = 0; s < 64; ++s) {
            const unsigned int k2 = key[s];
            if (k2 != 0u) mn = min(mn, k2);
        }
        #pragma unroll
        for (int off = 1; off < 64; off <<= 1)
            mn = min(mn, (unsigned int)__shfl_xor((int)mn, off, 64));

        auto cnt_lt = [&](unsigned int T) -> unsigned int {
            unsigned int c = 0;
            #pragma unroll
            for (int s = 0; s < 64; ++s) c += (key[s] < T) ? 1u : 0u;
            #pragma unroll
            for (int off = 1; off < 64; off <<= 1)
                c += (unsigned int)__shfl_xor((int)c, off, 64);
            return c;
        };

        // ---- gallop up by accelerating octaves until count >= K ----
        unsigned int L = mn & 0xFF800000u;
        unsigned int H = L;
        unsigned int stepOct = 1u << 23;
        unsigned int c;
        do {
            unsigned int Hn = H + stepOct;
            if (Hn > 0x7F800000u || Hn < H) Hn = 0x7F800000u;
            L = H; H = Hn;
            stepOct <<= 1;
            c = cnt_lt(H);
        } while (c < KNN);

        // ---- binary refine until pool fits in 64 lanes ----
        while (c > 64u && (H - L) > 1u) {
            const unsigned int M = L + ((H - L) >> 1);
            const unsigned int cm = cnt_lt(M);
            if (cm >= KNN) { H = M; c = cm; } else { L = M; }
        }

        // ---- pool build: all keys < H appended to per-wave LDS pool ----
        if (lane == 0) s_cnt[wv] = 0u;
        WFENCE();
        #pragma unroll
        for (int s = 0; s < 64; ++s) {
            if (key[s] < H) {
                const unsigned int p = atomicAdd(&s_cnt[wv], 1u);
                if (p < 64u) {
                    s_poolk[wv][p] = key[s];
                    s_pooli[wv][p] = (unsigned int)((s << 6) + lane);
                }
            }
        }
        WFENCE();
        unsigned int m = s_cnt[wv];
        if (m > 64u) m = 64u;

        unsigned int myk, myj;
        if ((unsigned int)lane < m) {
            myk = s_poolk[wv][lane];
            myj = s_pooli[wv][lane];
        } else {
            myk = 0xFFFFFFFFu;
            myj = (unsigned int)(NPTS + lane);   // unique, sorts last
        }

        // ---- 64-lane bitonic sort ascending by (key, idx) ----
        #pragma unroll
        for (int k = 2; k <= 64; k <<= 1) {
            #pragma unroll
            for (int jj = k >> 1; jj >= 1; jj >>= 1) {
                const unsigned int ok = (unsigned int)__shfl_xor((int)myk, jj, 64);
                const unsigned int oj = (unsigned int)__shfl_xor((int)myj, jj, 64);
                const bool up      = ((lane & k) == 0);
                const bool first   = ((lane & jj) == 0);
                const bool wantmin = (first == up);
                const bool less    = (myk < ok) || (myk == ok && myj < oj);
                if (less != wantmin) { myk = ok; myj = oj; }
            }
        }
        // lanes 0..31 hold the 32 nearest neighbors' indices in myj

        // ---- neighbor deltas (lanes 0..31) -> readlane broadcast ----
        float dx = 0.f, dy = 0.f, dz = 0.f;
        if (lane < KNN) {
            const float4 Q = s_p[myj];
            dx = Q.x - P.x;
            dy = Q.y - P.y;
            dz = Q.z - P.z;
        }

        const float basev = tbv + pbv + fmaf(pw2, P.z, fmaf(pw1, P.y, pw0 * P.x));
        float mx = -3.0e38f;
        #pragma unroll
        for (int t = 0; t < KNN; ++t) {
            const float ndx = __builtin_bit_cast(float, __builtin_amdgcn_readlane(__builtin_bit_cast(int, dx), t));
            const float ndy = __builtin_bit_cast(float, __builtin_amdgcn_readlane(__builtin_bit_cast(int, dy), t));
            const float ndz = __builtin_bit_cast(float, __builtin_amdgcn_readlane(__builtin_bit_cast(int, dz), t));
            const float proj = fmaf(tw2, ndz, fmaf(tw1, ndy, tw0 * ndx));
            mx = fmaxf(mx, proj);
        }
        out[(((size_t)b * NPTS + (size_t)i) << 6) + lane] = mx + basev;
        WFENCE();   // pool LDS reused next r-iteration (wave-local ordering)
    }
}

extern "C" void kernel_launch(void* const* d_in, const int* in_sizes, int n_in,
                              void* d_out, int out_size, void* d_ws, size_t ws_size,
                              hipStream_t stream) {
    const float* x  = (const float*)d_in[0];
    const float* tw = (const float*)d_in[1];
    const float* tb = (const float*)d_in[2];
    const float* pw = (const float*)d_in[3];
    const float* pb = (const float*)d_in[4];
    float* out = (float*)d_out;

    dim3 grid(8 * (NPTS / 32));   // 1024 WGs: 128 per batch, 32 points each
    dim3 block(512);
    hipLaunchKernelGGL(edgeconv_knn_kernel, grid, block, 0, stream,
                       x, tw, tb, pw, pb, out);
}

// Round 5
// 155.656 us; speedup vs baseline: 2.3763x; 1.1989x over previous
//
#include <hip/hip_runtime.h>

// EdgeConv with KNN graph: B=8, N=4096, D=3, E=64, K=32.
// One wave per point. Batch staged in LDS as float4 (x,y,z,sq); sq uses the
// same fmaf chain as the query so self-dist is exactly 0. 64 candidate keys
// per lane in registers (FULL unroll everywhere + (512,4) budget: R2/R3
// showed partial unroll or tight budget -> scratch spill, 330-955 MB HBM).
// Exact top-32:
//   1) per-lane min over keys -> 64-lane bitonic sort of minima -> sorted[32]
//      is a quantile-accurate starting threshold (R4 post-mortem: 19 blind
//      probes were 55% of VALU; sampling cuts to ~5-8),
//   2) ballot-based count-below (v_cmp -> sgpr + s_bcnt1, wave-uniform,
//      no shuffle-tree latency chain) for gallop + binary refine,
//   3) ballot+mbcnt compaction of survivors (<=64) into per-wave LDS pool,
//   4) 64-lane bitonic sort by (key, idx) -> lanes 0..31 = K nearest with
//      jax.lax.top_k's lower-index tie-break.

#define NPTS 4096
#define KNN  32

#define WFENCE() __asm__ volatile("s_waitcnt lgkmcnt(0)" ::: "memory")

__device__ __forceinline__ unsigned lane_prefix(unsigned long long m) {
    // popcount of m restricted to lanes below this lane
    return __builtin_amdgcn_mbcnt_hi((unsigned)(m >> 32),
           __builtin_amdgcn_mbcnt_lo((unsigned)m, 0u));
}

__global__ __launch_bounds__(512, 4)
void edgeconv_knn_kernel(const float* __restrict__ x,
                         const float* __restrict__ theta_w,
                         const float* __restrict__ theta_b,
                         const float* __restrict__ phi_w,
                         const float* __restrict__ phi_b,
                         float* __restrict__ out)
{
    __shared__ float4 s_p[NPTS];               // 64 KB: x,y,z,sq
    __shared__ unsigned int s_poolk[8][64];    // 2 KB  per-wave pool keys
    __shared__ unsigned int s_pooli[8][64];    // 2 KB  per-wave pool indices

    const int tid  = threadIdx.x;
    const int wv   = tid >> 6;
    const int lane = tid & 63;

    const int b  = blockIdx.x >> 7;            // 128 WGs per batch
    const int i0 = (blockIdx.x & 127) << 5;    // 32 points per WG

    // lane == output channel e
    const float tw0 = theta_w[lane];
    const float tw1 = theta_w[64 + lane];
    const float tw2 = theta_w[128 + lane];
    const float tbv = theta_b[lane];
    const float pw0 = phi_w[lane];
    const float pw1 = phi_w[64 + lane];
    const float pw2 = phi_w[128 + lane];
    const float pbv = phi_b[lane];

    const float* xb = x + (size_t)b * NPTS * 3;
    for (int p = tid; p < NPTS; p += 512) {
        const float px = xb[p * 3 + 0];
        const float py = xb[p * 3 + 1];
        const float pz = xb[p * 3 + 2];
        const float sq = fmaf(pz, pz, fmaf(py, py, px * px));
        s_p[p] = make_float4(px, py, pz, sq);
    }
    __syncthreads();

    for (int r = 0; r < 4; ++r) {
        const int i = i0 + wv * 4 + r;
        const float4 P = s_p[i];               // x,y,z,sq of query point

        // ---- phase A: 64 distance keys per lane + per-lane min ----
        unsigned int key[64];
        unsigned int mnv = 0xFFFFFFFFu;
        #pragma unroll
        for (int s = 0; s < 64; ++s) {
            const float4 Q = s_p[(s << 6) + lane];
            const float dt = fmaf(P.z, Q.z, fmaf(P.y, Q.y, P.x * Q.x));
            float dist = (P.w + Q.w) - 2.0f * dt;
            dist = fmaxf(dist, 0.0f);          // nonneg -> uint order == float order
            key[s] = __float_as_uint(dist);
            mnv = min(mnv, key[s]);
        }

        // ---- bitonic sort of the 64 lane-minima -> sampled threshold ----
        {
            unsigned int v = mnv;
            #pragma unroll
            for (int k = 2; k <= 64; k <<= 1) {
                #pragma unroll
                for (int jj = k >> 1; jj >= 1; jj >>= 1) {
                    const unsigned int o = (unsigned int)__shfl_xor((int)v, jj, 64);
                    const bool up      = ((lane & k) == 0);
                    const bool first   = ((lane & jj) == 0);
                    const bool wantmin = (first == up);
                    const bool less    = (v < o);
                    if (less != wantmin) v = o;
                }
            }
            mnv = v;   // sorted ascending across lanes
        }

        // wave-uniform count of keys strictly below T (ballot -> scalar)
        auto cnt_lt = [&](unsigned int T) -> unsigned int {
            unsigned int c = 0;
            #pragma unroll
            for (int s = 0; s < 64; ++s)
                c += (unsigned int)__popcll(__ballot(key[s] < T));
            return c;
        };

        // ---- bracket: start at 33rd-smallest lane-min ----
        unsigned int L = 0u;
        unsigned int H = (unsigned int)__builtin_amdgcn_readlane((int)mnv, 32);
        unsigned int c = cnt_lt(H);

        if (c < KNN) {                 // too low: gallop up by octaves
            unsigned int step = 1u << 23;
            do {
                unsigned int Hn = H + step;
                if (Hn > 0x7F800000u || Hn < H) Hn = 0x7F800000u;
                L = H; H = Hn;
                step <<= 1;
                c = cnt_lt(H);
            } while (c < KNN);
        }
        // ---- binary refine until pool fits in 64 lanes ----
        while (c > 64u && (H - L) > 1u) {
            const unsigned int M = L + ((H - L) >> 1);
            const unsigned int cm = cnt_lt(M);
            if (cm >= KNN) { H = M; c = cm; } else { L = M; }
        }

        // ---- pool build: ballot+mbcnt compaction (no atomics) ----
        unsigned int base = 0;
        #pragma unroll
        for (int s = 0; s < 64; ++s) {
            const bool pred = key[s] < H;
            const unsigned long long bm = __ballot(pred);
            if (bm) {
                if (pred) {
                    const unsigned int pos = base + lane_prefix(bm);
                    if (pos < 64u) {
                        s_poolk[wv][pos] = key[s];
                        s_pooli[wv][pos] = (unsigned int)((s << 6) + lane);
                    }
                }
                base += (unsigned int)__popcll(bm);
            }
        }
        WFENCE();
        unsigned int m = base;
        if (m > 64u) m = 64u;

        unsigned int myk, myj;
        if ((unsigned int)lane < m) {
            myk = s_poolk[wv][lane];
            myj = s_pooli[wv][lane];
        } else {
            myk = 0xFFFFFFFFu;
            myj = (unsigned int)(NPTS + lane);   // unique, sorts last
        }

        // ---- 64-lane bitonic sort ascending by (key, idx) ----
        #pragma unroll
        for (int k = 2; k <= 64; k <<= 1) {
            #pragma unroll
            for (int jj = k >> 1; jj >= 1; jj >>= 1) {
                const unsigned int ok = (unsigned int)__shfl_xor((int)myk, jj, 64);
                const unsigned int oj = (unsigned int)__shfl_xor((int)myj, jj, 64);
                const bool up      = ((lane & k) == 0);
                const bool first   = ((lane & jj) == 0);
                const bool wantmin = (first == up);
                const bool less    = (myk < ok) || (myk == ok && myj < oj);
                if (less != wantmin) { myk = ok; myj = oj; }
            }
        }
        // lanes 0..31 hold the 32 nearest neighbors' indices in myj

        // ---- neighbor deltas (lanes 0..31) -> readlane broadcast ----
        float dx = 0.f, dy = 0.f, dz = 0.f;
        if (lane < KNN) {
            const float4 Q = s_p[myj];
            dx = Q.x - P.x;
            dy = Q.y - P.y;
            dz = Q.z - P.z;
        }

        const float basev = tbv + pbv + fmaf(pw2, P.z, fmaf(pw1, P.y, pw0 * P.x));
        float mx = -3.0e38f;
        #pragma unroll
        for (int t = 0; t < KNN; ++t) {
            const float ndx = __builtin_bit_cast(float, __builtin_amdgcn_readlane(__builtin_bit_cast(int, dx), t));
            const float ndy = __builtin_bit_cast(float, __builtin_amdgcn_readlane(__builtin_bit_cast(int, dy), t));
            const float ndz = __builtin_bit_cast(float, __builtin_amdgcn_readlane(__builtin_bit_cast(int, dz), t));
            const float proj = fmaf(tw2, ndz, fmaf(tw1, ndy, tw0 * ndx));
            mx = fmaxf(mx, proj);
        }
        out[(((size_t)b * NPTS + (size_t)i) << 6) + lane] = mx + basev;
        WFENCE();   // pool LDS reused next r-iteration (wave-local ordering)
    }
}

extern "C" void kernel_launch(void* const* d_in, const int* in_sizes, int n_in,
                              void* d_out, int out_size, void* d_ws, size_t ws_size,
                              hipStream_t stream) {
    const float* x  = (const float*)d_in[0];
    const float* tw = (const float*)d_in[1];
    const float* tb = (const float*)d_in[2];
    const float* pw = (const float*)d_in[3];
    const float* pb = (const float*)d_in[4];
    float* out = (float*)d_out;

    dim3 grid(8 * (NPTS / 32));   // 1024 WGs: 128 per batch, 32 points each
    dim3 block(512);
    hipLaunchKernelGGL(edgeconv_knn_kernel, grid, block, 0, stream,
                       x, tw, tb, pw, pb, out);
}